// Round 9
// baseline (436.681 us; speedup 1.0000x reference)
//
#include <hip/hip_runtime.h>
#include <hip/hip_bf16.h>

#define Bn 2
#define Tn 4096
#define Cn 768
#define Hn 12
#define Dn 64
#define Mn (Bn * Tn)   // 8192
#define PAD 72         // padded LDS row stride (bf16 elems) for attn/transpose

typedef __attribute__((ext_vector_type(8))) short bf16x8;
typedef __attribute__((ext_vector_type(4))) float f32x4;

typedef const __attribute__((address_space(1))) unsigned int* gas_ptr;
typedef __attribute__((address_space(3))) unsigned int* las_ptr;

__device__ __forceinline__ float b2f(unsigned short u) {
    return __uint_as_float(((unsigned int)u) << 16);
}
__device__ __forceinline__ unsigned short f2b(float f) {
    unsigned int x = __float_as_uint(f);
    x += 0x7FFFu + ((x >> 16) & 1u);   // round-to-nearest-even
    return (unsigned short)(x >> 16);
}

// Async global->LDS, 16B/lane. LDS dest = wave-uniform base + lane*16.
__device__ __forceinline__ void async_ld16(const unsigned short* g, unsigned short* l) {
    __builtin_amdgcn_global_load_lds((gas_ptr)(const void*)g, (las_ptr)(void*)l, 16, 0, 0);
}

// ---------------------------------------------------------------------------
// Input dtype detection (fp32 read as bf16 halves shows huge exponents).
// ---------------------------------------------------------------------------
__global__ void detect_k(const unsigned short* __restrict__ W, int* __restrict__ flag) {
    __shared__ int any;
    if (threadIdx.x == 0) any = 0;
    __syncthreads();
    int bad = 0;
    for (int i = threadIdx.x; i < 65536; i += 256) {
        const unsigned int e = (W[i] >> 7) & 0xFFu;
        bad |= (e >= 0x88u) ? 1 : 0;
    }
    if (bad) atomicOr(&any, 1);
    __syncthreads();
    if (threadIdx.x == 0) *flag = any;
}

// Convert x (fp32 or bf16 per flag) -> bf16 flat copy. 8 elems/thread.
__global__ __launch_bounds__(256) void convert_x_k(
    const void* __restrict__ in, unsigned short* __restrict__ out,
    const int* __restrict__ flag)
{
    const size_t i = ((size_t)blockIdx.x * 256 + threadIdx.x) * 8;
    union { int4 v; unsigned short u[8]; } pk;
    if (*flag) {
        const float* p = (const float*)in + i;
        float4 a = *reinterpret_cast<const float4*>(p);
        float4 b = *reinterpret_cast<const float4*>(p + 4);
        float t[8] = {a.x, a.y, a.z, a.w, b.x, b.y, b.z, b.w};
#pragma unroll
        for (int j = 0; j < 8; ++j) pk.u[j] = f2b(t[j]);
    } else {
        pk.v = *reinterpret_cast<const int4*>((const unsigned short*)in + i);
    }
    *reinterpret_cast<int4*>(out + i) = pk.v;
}

// Transpose weight: in[K][N] (fp32 or bf16 per flag) -> out[N][K] bf16. 64x64 tiles.
__global__ __launch_bounds__(256) void transpose_w_k(
    const void* __restrict__ in, unsigned short* __restrict__ out,
    int K, int N, const int* __restrict__ flag)
{
    __shared__ unsigned short Ts[64][PAD];   // [n][k]
    const int tid = threadIdx.x;
    const int kB = blockIdx.y * 64, nB = blockIdx.x * 64;
    const bool f32 = (*flag != 0);
#pragma unroll
    for (int it = 0; it < 2; ++it) {
        const int r = (tid >> 3) + it * 32;   // k-row in tile
        const int c = (tid & 7) * 8;          // n-col chunk
        float t[8];
        if (f32) {
            const float* p = (const float*)in + (size_t)(kB + r) * N + nB + c;
            float4 a = *reinterpret_cast<const float4*>(p);
            float4 b = *reinterpret_cast<const float4*>(p + 4);
            t[0]=a.x;t[1]=a.y;t[2]=a.z;t[3]=a.w;t[4]=b.x;t[5]=b.y;t[6]=b.z;t[7]=b.w;
        } else {
            int4 v = *reinterpret_cast<const int4*>((const unsigned short*)in + (size_t)(kB + r) * N + nB + c);
            const unsigned short* u = reinterpret_cast<const unsigned short*>(&v);
#pragma unroll
            for (int j = 0; j < 8; ++j) t[j] = b2f(u[j]);
        }
#pragma unroll
        for (int j = 0; j < 8; ++j) Ts[c + j][r] = f2b(t[j]);
    }
    __syncthreads();
#pragma unroll
    for (int it = 0; it < 2; ++it) {
        const int n = (tid >> 3) + it * 32;
        const int k = (tid & 7) * 8;
        *reinterpret_cast<int4*>(out + (size_t)(nB + n) * K + kB + k) =
            *reinterpret_cast<const int4*>(&Ts[n][k]);
    }
}

// ---------------------------------------------------------------------------
// m97-style MFMA GEMM: C[M,N] = A[M,K]*Bt[N,K]^T, A/Bt bf16, fp32 accum.
// 128x128 tile, BK=64, 4 waves (64x64 quadrant each). A/B tiles staged into
// LDS in MFMA-FRAGMENT ORDER via global_load_lds (16B/lane). Fragment read =
// ds_read_b128 at chunk + lane*16 (conflict-free).
// EPI==0: row-major store (fp32 if flag else bf16). EPI==1: QKV split, bf16.
// ---------------------------------------------------------------------------
template <int EPI>
__global__ __launch_bounds__(256) void gemm_lds(
    const unsigned short* __restrict__ A, const unsigned short* __restrict__ Bt,
    void* __restrict__ Out, unsigned short* __restrict__ Qo,
    unsigned short* __restrict__ Ko, unsigned short* __restrict__ Vo,
    int M, int N, int K, const int* __restrict__ flag)
{
    __shared__ unsigned short As[8192];   // 16 chunks x 512 elems
    __shared__ unsigned short Bs[8192];
    const int tid = threadIdx.x;
    const int w = tid >> 6, l = tid & 63;
    const int l15 = l & 15, l4 = l >> 4;
    const int rowBase = blockIdx.y * 128;
    const int colBase = blockIdx.x * 128;
    const int mq = (w & 1) * 64, nq = (w >> 1) * 64;
    const bool f32 = (*flag != 0);

    const int laneRow = l15, laneK = l4 * 8;

    f32x4 acc[4][4];
#pragma unroll
    for (int i = 0; i < 4; ++i)
#pragma unroll
        for (int j = 0; j < 4; ++j) acc[i][j] = (f32x4){0.f, 0.f, 0.f, 0.f};

    for (int k0 = 0; k0 < K; k0 += 64) {
        __syncthreads();   // prior iteration's fragment reads complete
#pragma unroll
        for (int j = 0; j < 4; ++j) {
            const int c = w * 4 + j;
            const int mt_g = c >> 1, kh = c & 1;
            const size_t ga = (size_t)(rowBase + mt_g * 16 + laneRow) * K + k0 + kh * 32 + laneK;
            const size_t gb = (size_t)(colBase + mt_g * 16 + laneRow) * K + k0 + kh * 32 + laneK;
            async_ld16(A + ga, &As[c * 512]);
            async_ld16(Bt + gb, &Bs[c * 512]);
        }
        __syncthreads();   // drains vmcnt: DMA complete

#pragma unroll
        for (int kh = 0; kh < 2; ++kh) {
            bf16x8 af[4], bf[4];
#pragma unroll
            for (int mt = 0; mt < 4; ++mt)
                af[mt] = *reinterpret_cast<const bf16x8*>(
                    &As[(((mq >> 4) + mt) * 2 + kh) * 512 + l * 8]);
#pragma unroll
            for (int nt = 0; nt < 4; ++nt)
                bf[nt] = *reinterpret_cast<const bf16x8*>(
                    &Bs[(((nq >> 4) + nt) * 2 + kh) * 512 + l * 8]);
#pragma unroll
            for (int mt = 0; mt < 4; ++mt)
#pragma unroll
                for (int nt = 0; nt < 4; ++nt)
                    acc[mt][nt] = __builtin_amdgcn_mfma_f32_16x16x32_bf16(af[mt], bf[nt], acc[mt][nt], 0, 0, 0);
        }
    }

    // epilogue: C/D layout col=l15, row=l4*4+i
#pragma unroll
    for (int mt = 0; mt < 4; ++mt)
#pragma unroll
        for (int i = 0; i < 4; ++i) {
            const int m = rowBase + mq + mt * 16 + l4 * 4 + i;
#pragma unroll
            for (int nt = 0; nt < 4; ++nt) {
                const int n0 = colBase + nq + nt * 16 + l15;
                if (EPI == 0) {
                    if (f32) ((float*)Out)[(size_t)m * N + n0] = acc[mt][nt][i];
                    else ((unsigned short*)Out)[(size_t)m * N + n0] = f2b(acc[mt][nt][i]);
                } else {
                    const int sec = n0 / 768;
                    const int cc = n0 - sec * 768;
                    const int h = cc >> 6, d = cc & 63;
                    const int b = m >> 12, t = m & 4095;
                    unsigned short* dst = (sec == 0) ? Qo : (sec == 1) ? Ko : Vo;
                    dst[(((size_t)(b * Hn + h) * Tn + t) * Dn) + d] = f2b(acc[mt][nt][i]);
                }
            }
        }
}

// ---------------------------------------------------------------------------
// MFMA flash attention, fixed-max softmax, 2 barriers/stage (round-8 verified).
// ---------------------------------------------------------------------------
__global__ __launch_bounds__(512, 5) void attn_mfma(
    const unsigned short* __restrict__ Q, const unsigned short* __restrict__ K,
    const unsigned short* __restrict__ V, unsigned short* __restrict__ Y)
{
    __shared__ unsigned short Ks[64 * PAD];    // [key][d]
    __shared__ unsigned short Vt[64 * PAD];    // [d][key]
    __shared__ unsigned short Ps[128 * PAD];   // [q-row][key]

    const int tid = threadIdx.x;
    const int w = tid >> 6, l = tid & 63;      // 8 waves
    const int l15 = l & 15, l4 = l >> 4;
    const int qb = (int)gridDim.x - 1 - (int)blockIdx.x;  // heavy blocks first
    const int bh = blockIdx.y;
    const int q0 = qb * 128;
    const size_t base = (size_t)bh * Tn * Dn;
    const float sc = 0.125f * 1.44269504088896f;   // D^-0.5 * log2(e)

    bf16x8 aq[2];
#pragma unroll
    for (int kh = 0; kh < 2; ++kh)
        aq[kh] = *reinterpret_cast<const bf16x8*>(
            Q + base + (size_t)(q0 + w * 16 + l15) * Dn + kh * 32 + l4 * 8);

    f32x4 o[4];
#pragma unroll
    for (int dt = 0; dt < 4; ++dt) o[dt] = (f32x4){0.f, 0.f, 0.f, 0.f};
    float l_i[4] = {0.f, 0.f, 0.f, 0.f};

    const int kend = q0 + 128;
    for (int k0 = 0; k0 < kend; k0 += 64) {
        __syncthreads();   // prior stage's Ks/Vt reads complete
        {   // stage K row-major
            const int r = tid >> 3, c = (tid & 7) * 8;
            *reinterpret_cast<int4*>(&Ks[r * PAD + c]) =
                *reinterpret_cast<const int4*>(K + base + (size_t)(k0 + r) * Dn + c);
        }
        {   // stage V transposed: lane-contiguous keys (conflict-free stores)
            const int r = tid & 63, d0 = (tid >> 6) * 8;
            int4 vv = *reinterpret_cast<const int4*>(V + base + (size_t)(k0 + r) * Dn + d0);
            const unsigned short* vu = reinterpret_cast<const unsigned short*>(&vv);
#pragma unroll
            for (int j = 0; j < 8; ++j) Vt[(d0 + j) * PAD + r] = vu[j];
        }
        __syncthreads();

        // S = Q K^T
        f32x4 sfr[4];
#pragma unroll
        for (int tt = 0; tt < 4; ++tt) {
            bf16x8 bk0 = *reinterpret_cast<const bf16x8*>(&Ks[(tt * 16 + l15) * PAD + l4 * 8]);
            bf16x8 bk1 = *reinterpret_cast<const bf16x8*>(&Ks[(tt * 16 + l15) * PAD + 32 + l4 * 8]);
            f32x4 z = (f32x4){0.f, 0.f, 0.f, 0.f};
            z = __builtin_amdgcn_mfma_f32_16x16x32_bf16(aq[0], bk0, z, 0, 0, 0);
            z = __builtin_amdgcn_mfma_f32_16x16x32_bf16(aq[1], bk1, z, 0, 0, 0);
            sfr[tt] = z;
        }

        // p = exp2(s*sc) with causal mask; accumulate l per-lane
        const bool need_mask = (k0 + 63 > q0);
        float p[4][4];
#pragma unroll
        for (int tt = 0; tt < 4; ++tt) {
            const int cb = k0 + tt * 16 + l15;
            const int rb = q0 + w * 16 + l4 * 4;
#pragma unroll
            for (int i = 0; i < 4; ++i) {
                float s = sfr[tt][i] * sc;
                if (need_mask && (cb > rb + i)) s = -1e30f;
                const float e = exp2f(s);
                p[tt][i] = e;
                l_i[i] += e;
            }
        }

        // P: C-layout -> LDS [row][key] (wave-private strip; no barrier needed)
#pragma unroll
        for (int tt = 0; tt < 4; ++tt)
#pragma unroll
            for (int i = 0; i < 4; ++i)
                Ps[(w * 16 + l4 * 4 + i) * PAD + tt * 16 + l15] = f2b(p[tt][i]);

        bf16x8 ap0 = *reinterpret_cast<const bf16x8*>(&Ps[(w * 16 + l15) * PAD + l4 * 8]);
        bf16x8 ap1 = *reinterpret_cast<const bf16x8*>(&Ps[(w * 16 + l15) * PAD + 32 + l4 * 8]);
#pragma unroll
        for (int dt = 0; dt < 4; ++dt) {
            bf16x8 bv0 = *reinterpret_cast<const bf16x8*>(&Vt[(dt * 16 + l15) * PAD + l4 * 8]);
            bf16x8 bv1 = *reinterpret_cast<const bf16x8*>(&Vt[(dt * 16 + l15) * PAD + 32 + l4 * 8]);
            o[dt] = __builtin_amdgcn_mfma_f32_16x16x32_bf16(ap0, bv0, o[dt], 0, 0, 0);
            o[dt] = __builtin_amdgcn_mfma_f32_16x16x32_bf16(ap1, bv1, o[dt], 0, 0, 0);
        }
    }

    // epilogue: reduce l across the 16 lanes sharing each row, then write Y
#pragma unroll
    for (int i = 0; i < 4; ++i)
#pragma unroll
        for (int off = 1; off < 16; off <<= 1) l_i[i] += __shfl_xor(l_i[i], off);

    const int b = bh / Hn, h = bh - b * Hn;
#pragma unroll
    for (int i = 0; i < 4; ++i) {
        const float inv = 1.0f / l_i[i];
        const int row = q0 + w * 16 + l4 * 4 + i;
#pragma unroll
        for (int dt = 0; dt < 4; ++dt)
            Y[((size_t)(b * Tn + row)) * Cn + h * 64 + dt * 16 + l15] = f2b(o[dt][i] * inv);
    }
}

extern "C" void kernel_launch(void* const* d_in, const int* in_sizes, int n_in,
                              void* d_out, int out_size, void* d_ws, size_t ws_size,
                              hipStream_t stream)
{
    const void* x = d_in[0];
    const void* wqkv = d_in[1];
    const void* wproj = d_in[2];
    const size_t HSZ = (size_t)Bn * Hn * Tn * Dn;   // 6291456 elems
    // Workspace (proven 50.3 MB layout):
    //   [0,HSZ)      q    (dead after attn -> wprojT)
    //   [HSZ,2HSZ)   k
    //   [2HSZ,3HSZ)  v
    //   [3HSZ,4HSZ)  wqkvT (during QKV gemm) then y (attn output)
    //   [4HSZ]       flag
    // xb (bf16 copy of x, 12.6 MB) lives in d_out (25 MB fp32): consumed by
    // the QKV GEMM, long dead before the proj GEMM overwrites d_out.
    unsigned short* q = (unsigned short*)d_ws;
    unsigned short* k = q + HSZ;
    unsigned short* v = k + HSZ;
    unsigned short* R = v + HSZ;
    unsigned short* wqkvT = R;            // [2304][768] = 1769472 elems <= HSZ
    unsigned short* y = R;
    unsigned short* wprojT = q;           // [768][768], reused after attn
    unsigned short* xb = (unsigned short*)d_out;   // 6291456 elems = 12.6 MB <= 25 MB
    int* flag = (int*)(R + HSZ);

    detect_k<<<1, 256, 0, stream>>>((const unsigned short*)wqkv, flag);
    convert_x_k<<<(Mn * Cn) / (256 * 8), 256, 0, stream>>>(x, xb, flag);
    transpose_w_k<<<dim3(3 * Cn / 64, Cn / 64), 256, 0, stream>>>(wqkv, wqkvT, Cn, 3 * Cn, flag);
    gemm_lds<1><<<dim3(3 * Cn / 128, Mn / 128), 256, 0, stream>>>(
        xb, wqkvT, nullptr, q, k, v, Mn, 3 * Cn, Cn, flag);
    attn_mfma<<<dim3(Tn / 128, Bn * Hn), 512, 0, stream>>>(q, k, v, y);
    transpose_w_k<<<dim3(Cn / 64, Cn / 64), 256, 0, stream>>>(wproj, wprojT, Cn, Cn, flag);
    gemm_lds<0><<<dim3(Cn / 128, Mn / 128), 256, 0, stream>>>(
        y, wprojT, d_out, nullptr, nullptr, nullptr, Mn, Cn, Cn, flag);
}